// Round 2
// baseline (1223.381 us; speedup 1.0000x reference)
//
#include <hip/hip_runtime.h>
#include <math.h>

#define LL 64
#define NB 64
#define NSITE 4096
#define BN 262144
// ws float layout:
//  [0,640)     red[b*10 + {S1,S2,Sd1_c0..3,Sd2_c0..3}]   (atomically accumulated)
//  [640,704)   lapl[b]                                   (atomically accumulated)
//  [704,1344)  coef[b*10 + {alpha,beta,ad_c0..3,bd_c0..3}]
//  [1344, +6*BN) planes: h, RA, RB, TAa, TAb, TBb

// exact GELU: value, first and second derivative
__device__ __forceinline__ void gelu3(float u, float &h, float &d, float &e){
  float Phi = 0.5f * (1.0f + erff(u * 0.70710678118654752f));
  float phi = 0.3989422804014327f * __expf(-0.5f * u * u);
  h = u * Phi;
  d = Phi + u * phi;
  e = phi * (2.0f - u * u);
}

__device__ __forceinline__ float redjb16(float v){
  v += __shfl_xor(v, 1);  v += __shfl_xor(v, 2);
  v += __shfl_xor(v, 4);  v += __shfl_xor(v, 8);
  return v;
}
__device__ __forceinline__ float red32(float v){
  v += __shfl_xor(v, 1);  v += __shfl_xor(v, 2);
  v += __shfl_xor(v, 4);  v += __shfl_xor(v, 8);
  v += __shfl_xor(v, 16);
  return v;
}
__device__ __forceinline__ float red64(float v){
  v += __shfl_xor(v, 1);  v += __shfl_xor(v, 2);
  v += __shfl_xor(v, 4);  v += __shfl_xor(v, 8);
  v += __shfl_xor(v, 16); v += __shfl_xor(v, 32);
  return v;
}

// ---------------- heavy kernel: one (batch, row, half-row) tile of 32 sites ----------------
__global__ __launch_bounds__(256, 1) void k_c1(
    const float* __restrict__ xg, const int* __restrict__ signs,
    const float* __restrict__ W1g, const float* __restrict__ b1g,
    const float* __restrict__ W2g, const float* __restrict__ b2g,
    const float* __restrict__ W3g, const float* __restrict__ b3g,
    float* __restrict__ ws)
{
  __shared__ float W2L[16384];   // 64 KB fp32
  __shared__ float h1T[4096];    // [k][s]  16 KB
  __shared__ float d1T[4096];
  __shared__ float e1T[4096];
  __shared__ float waL[128], wbL[128], b1L[128], b2L[128], w3L[128];
  __shared__ float pL[32], lL[32];
  __shared__ float xr0[64], xrm[32], xrp[32];
  __shared__ float zv0[64], zvm[32], zvp[32];
  __shared__ float hsL[32], RAsL[32], RBsL[32];

  const int tid = threadIdx.x;
  const int bi  = blockIdx.x;
  const int b = bi >> 7;
  const int rem = bi & 127;
  const int i = rem >> 1;
  const int jbase = (rem & 1) << 5;
  const int im = (i + 63) & 63, ip = (i + 1) & 63;

  // ---- P0: stage weights & row data ----
  {
    const float4* s4 = (const float4*)W2g;
    float4* d4 = (float4*)W2L;
    #pragma unroll
    for (int t = 0; t < 16; ++t) d4[tid + 256*t] = s4[tid + 256*t];
  }
  if (tid < 128) {
    int k = tid;
    waL[k] = W1g[k] + W1g[256+k] + W1g[384+k];
    wbL[k] = W1g[128+k];
    b1L[k] = b1g[k];
    b2L[k] = b2g[k];
    w3L[k] = W3g[k];
  }
  if (tid < 64) {
    int j = tid;
    xr0[j] = xg[(size_t)b*NSITE + i*64 + j];
    int c0 = ((i & 1) << 1) | (j & 1);
    zv0[j] = 2.0f * (float)signs[((c0*NB + b)*LL + i)*LL + j] - 1.0f;
  }
  if (tid < 32) {
    int j = jbase + tid;
    xrm[tid] = xg[(size_t)b*NSITE + im*64 + j];
    xrp[tid] = xg[(size_t)b*NSITE + ip*64 + j];
    int cm = ((im & 1) << 1) | (j & 1);
    int cp = ((ip & 1) << 1) | (j & 1);
    zvm[tid] = 2.0f * (float)signs[((cm*NB + b)*LL + im)*LL + j] - 1.0f;
    zvp[tid] = 2.0f * (float)signs[((cp*NB + b)*LL + ip)*LL + j] - 1.0f;
  }
  __syncthreads();
  if (tid < 32) {
    int jg = jbase + tid, jm = (jg+63)&63, jp = (jg+1)&63;
    pL[tid] = xr0[jg];
    lL[tid] = xrm[tid] + xrp[tid] + xr0[jm] + xr0[jp] - 4.0f*xr0[jg];
  }
  __syncthreads();

  // ---- P1: layer-1 elementwise (u1 = p*wa + l*wb + b1) ----
  for (int it = 0; it < 16; ++it) {
    int idx = it*256 + tid;
    int s = idx & 31, k = idx >> 5;
    float u = pL[s]*waL[k] + lL[s]*wbL[k] + b1L[k];
    float h, d, e;
    gelu3(u, h, d, e);
    h1T[k*32+s] = h;
    d1T[k*32+s] = d;
    e1T[k*32+s] = e;
  }
  __syncthreads();

  // ---- P2 pass A: u2 = h1@W2, U2A = (d1*wa)@W2, U2B = (d1*wb)@W2 ----
  const int jb = tid & 15, sb = tid >> 4;
  const int j0 = jb*8, s0 = sb*2;
  float u2[2][8], Ua[2][8], Ub[2][8];
  #pragma unroll
  for (int s = 0; s < 2; ++s)
    #pragma unroll
    for (int j = 0; j < 8; ++j) { u2[s][j]=0.f; Ua[s][j]=0.f; Ub[s][j]=0.f; }

  for (int k = 0; k < 128; ++k) {
    float2 h1v = *(const float2*)&h1T[k*32 + s0];
    float2 d1v = *(const float2*)&d1T[k*32 + s0];
    float wk = waL[k], wbk = wbL[k];
    float4 wv0 = *(const float4*)&W2L[k*128 + j0];
    float4 wv1 = *(const float4*)&W2L[k*128 + j0 + 4];
    float wf[8] = {wv0.x, wv0.y, wv0.z, wv0.w, wv1.x, wv1.y, wv1.z, wv1.w};
    const float* h1p = (const float*)&h1v;
    const float* d1p = (const float*)&d1v;
    #pragma unroll
    for (int s = 0; s < 2; ++s) {
      float hs = h1p[s];
      float da = d1p[s]*wk, db = d1p[s]*wbk;
      #pragma unroll
      for (int j = 0; j < 8; ++j) {
        u2[s][j] = fmaf(hs, wf[j], u2[s][j]);
        Ua[s][j] = fmaf(da, wf[j], Ua[s][j]);
        Ub[s][j] = fmaf(db, wf[j], Ub[s][j]);
      }
    }
  }

  // epilogue A: layer-2 gelu, per-site scalars from register dots
  float w3d2[2][8];
  float hp[2], RAp[2], RBp[2], Aap[2], Abp[2], Bbp[2];
  #pragma unroll
  for (int s = 0; s < 2; ++s) {
    hp[s]=0.f; RAp[s]=0.f; RBp[s]=0.f; Aap[s]=0.f; Abp[s]=0.f; Bbp[s]=0.f;
    #pragma unroll
    for (int j = 0; j < 8; ++j) {
      float uu = u2[s][j] + b2L[j0+j];
      float h2, d2, e2;
      gelu3(uu, h2, d2, e2);
      float w3 = w3L[j0+j];
      float wd = w3*d2, we = w3*e2;
      w3d2[s][j] = wd;
      float A = Ua[s][j], Bv = Ub[s][j];
      hp[s]  += w3*h2;
      RAp[s] += wd*A;
      RBp[s] += wd*Bv;
      Aap[s] += we*A*A;
      Abp[s] += we*A*Bv;
      Bbp[s] += we*Bv*Bv;
    }
  }
  #pragma unroll
  for (int s = 0; s < 2; ++s) {
    hp[s]  = redjb16(hp[s]);
    RAp[s] = redjb16(RAp[s]);
    RBp[s] = redjb16(RBp[s]);
    Aap[s] = redjb16(Aap[s]);
    Abp[s] = redjb16(Abp[s]);
    Bbp[s] = redjb16(Bbp[s]);
  }
  float b3v = b3g[0];
  if (jb == 0) {
    float* P = ws + 1344;
    #pragma unroll
    for (int s = 0; s < 2; ++s) {
      int sl = s0 + s;
      float hv = hp[s] + b3v;
      hsL[sl] = hv; RAsL[sl] = RAp[s]; RBsL[sl] = RBp[s];
      size_t site = (size_t)b*NSITE + i*64 + jbase + sl;
      P[0*BN + site] = hv;
      P[1*BN + site] = RAp[s];
      P[2*BN + site] = RBp[s];
    }
  }

  // ---- P2 pass B: E_aa=(wa^2*e1)@W2, E_ab=(wa*wb*e1)@W2, E_bb=(wb^2*e1)@W2 ----
  float Ea[2][8], Eb[2][8], Ec[2][8];
  #pragma unroll
  for (int s = 0; s < 2; ++s)
    #pragma unroll
    for (int j = 0; j < 8; ++j) { Ea[s][j]=0.f; Eb[s][j]=0.f; Ec[s][j]=0.f; }

  for (int k = 0; k < 128; ++k) {
    float2 e1v = *(const float2*)&e1T[k*32 + s0];
    float wk = waL[k], wbk = wbL[k];
    float waa = wk*wk, wab = wk*wbk, wbb = wbk*wbk;
    float4 wv0 = *(const float4*)&W2L[k*128 + j0];
    float4 wv1 = *(const float4*)&W2L[k*128 + j0 + 4];
    float wf[8] = {wv0.x, wv0.y, wv0.z, wv0.w, wv1.x, wv1.y, wv1.z, wv1.w};
    const float* e1p = (const float*)&e1v;
    #pragma unroll
    for (int s = 0; s < 2; ++s) {
      float ea = e1p[s]*waa, eb = e1p[s]*wab, ec = e1p[s]*wbb;
      #pragma unroll
      for (int j = 0; j < 8; ++j) {
        Ea[s][j] = fmaf(ea, wf[j], Ea[s][j]);
        Eb[s][j] = fmaf(eb, wf[j], Eb[s][j]);
        Ec[s][j] = fmaf(ec, wf[j], Ec[s][j]);
      }
    }
  }
  {
    float* P = ws + 1344;
    #pragma unroll
    for (int s = 0; s < 2; ++s) {
      float ta=0.f, tb=0.f, tc=0.f;
      #pragma unroll
      for (int j = 0; j < 8; ++j) {
        ta += w3d2[s][j]*Ea[s][j];
        tb += w3d2[s][j]*Eb[s][j];
        tc += w3d2[s][j]*Ec[s][j];
      }
      ta = redjb16(ta); tb = redjb16(tb); tc = redjb16(tc);
      if (jb == 0) {
        size_t site = (size_t)b*NSITE + i*64 + jbase + (s0 + s);
        P[3*BN + site] = Aap[s] + ta;
        P[4*BN + site] = Abp[s] + tb;
        P[5*BN + site] = Bbp[s] + tc;
      }
    }
  }

  __syncthreads();

  // ---- per-batch reductions: S1, S2, Sdot1_c, Sdot2_c (32 local sites) ----
  if (tid < 32) {
    int s = tid;
    int jg = jbase + s, jm = (jg+63)&63, jp = (jg+1)&63;
    float h  = hsL[s], RA = RAsL[s], RB = RBsL[s];
    int c0 = ((i & 1) << 1) | (jg & 1);
    float hd[4] = {0.f, 0.f, 0.f, 0.f};
    hd[c0]     = zv0[jg]*(RA - 4.0f*RB);
    hd[c0 ^ 1] = (zv0[jm] + zv0[jp])*RB;
    hd[c0 ^ 2] = (zvm[s] + zvp[s])*RB;
    float r[10];
    r[0] = h; r[1] = h*h;
    r[2] = hd[0]; r[3] = hd[1]; r[4] = hd[2]; r[5] = hd[3];
    r[6] = h*hd[0]; r[7] = h*hd[1]; r[8] = h*hd[2]; r[9] = h*hd[3];
    #pragma unroll
    for (int n = 0; n < 10; ++n) r[n] = red32(r[n]);
    if (s == 0) {
      #pragma unroll
      for (int n = 0; n < 10; ++n) atomicAdd(&ws[b*10 + n], r[n]);
    }
  }
}

// ---------------- tiny per-batch head calculus ----------------
__global__ __launch_bounds__(64, 1) void k_b(
    const float* __restrict__ aW1g, const float* __restrict__ ab1g,
    const float* __restrict__ aW2g, float* __restrict__ ws)
{
  int b = blockIdx.x, k = threadIdx.x;
  const float Nf = 4096.0f, Nm1 = 4095.0f;
  float S1 = ws[b*10+0], S2 = ws[b*10+1];
  float m = S1/Nf, q = S2/Nf;
  float v = (S2 - S1*S1/Nf)/Nm1;
  float w0 = aW1g[k], w1 = aW1g[64+k], w2 = aW1g[128+k];
  float t = m*w0 + v*w1 + q*w2 + ab1g[k];
  float gh, gd, ge;
  gelu3(t, gh, gd, ge);
  float o = aW2g[k];
  float g1o = gd*o, g2o = ge*o;
  float da0 = w0*g1o, da1 = w1*g1o, da2 = w2*g1o;
  float M00 = w0*w0*g2o, M01 = w0*w1*g2o, M02 = w0*w2*g2o;
  float M11 = w1*w1*g2o, M12 = w1*w2*g2o, M22 = w2*w2*g2o;
  da0 = red64(da0); da1 = red64(da1); da2 = red64(da2);
  M00 = red64(M00); M01 = red64(M01); M02 = red64(M02);
  M11 = red64(M11); M12 = red64(M12); M22 = red64(M22);
  if (k == 0) {
    float* coef = ws + 704 + b*10;
    coef[0] = da0/Nf - 2.0f*da1*m/Nm1;                 // alpha
    coef[1] = 2.0f*da1/Nm1 + 2.0f*da2/Nf;              // beta
    #pragma unroll
    for (int c = 0; c < 4; ++c) {
      float s1 = ws[b*10 + 2 + c], s2 = ws[b*10 + 6 + c];
      float md = s1/Nf, qd = 2.0f*s2/Nf;
      float vd = (2.0f*s2 - 2.0f*S1*s1/Nf)/Nm1;
      float dd0 = M00*md + M01*vd + M02*qd;
      float dd1 = M01*md + M11*vd + M12*qd;
      float dd2 = M02*md + M12*vd + M22*qd;
      coef[2+c] = dd0/Nf - 2.0f*(dd1*m + da1*md)/Nm1;  // alpha_dot_c
      coef[6+c] = 2.0f*dd1/Nm1 + 2.0f*dd2/Nf;          // beta_dot_c
    }
  }
}

// ---------------- scalar stencil: grad out + lapl accumulate ----------------
__global__ __launch_bounds__(256, 1) void k_c2(
    const int* __restrict__ signs, float* __restrict__ ws,
    float* __restrict__ out)
{
  __shared__ float part[4];
  int blk = blockIdx.x;
  int b = blk >> 4, rg = blk & 15;
  int tid = threadIdx.x;
  int rl = tid >> 6, j = tid & 63;
  int i = rg*4 + rl;
  const float* coef = ws + 704 + b*10;
  float alpha = coef[0], beta = coef[1];
  const float* P = ws + 1344;
  int base = b*NSITE;
  int im=(i+63)&63, ip=(i+1)&63, jm=(j+63)&63, jp=(j+1)&63;
  int s  = base + i*64 + j;
  int su = base + im*64 + j, sd = base + ip*64 + j;
  int sl = base + i*64 + jm, sr = base + i*64 + jp;
  float h  = P[s], RA = P[BN+s], RB = P[2*BN+s];
  float TAa= P[3*BN+s], TAb = P[4*BN+s], TBb = P[5*BN+s];
  float g  = alpha + beta*h;
  float cb  = g*RB;
  float cbu = (alpha + beta*P[su])*P[2*BN+su];
  float cbd = (alpha + beta*P[sd])*P[2*BN+sd];
  float cbl = (alpha + beta*P[sl])*P[2*BN+sl];
  float cbr = (alpha + beta*P[sr])*P[2*BN+sr];
  float grad = g*RA + (cbu + cbd + cbl + cbr - 4.0f*cb);
  out[(size_t)b*4097 + i*64 + j] = grad;

  int c0 = ((i & 1) << 1) | (j & 1);
  int c1 = c0 ^ 1, c2 = c0 ^ 2;
  float zv = 2.0f*(float)signs[((c0*NB + b)*LL + i )*LL + j ] - 1.0f;
  float zl = 2.0f*(float)signs[((c1*NB + b)*LL + i )*LL + jm] - 1.0f;
  float zr = 2.0f*(float)signs[((c1*NB + b)*LL + i )*LL + jp] - 1.0f;
  float zu = 2.0f*(float)signs[((c2*NB + b)*LL + im)*LL + j ] - 1.0f;
  float zd = 2.0f*(float)signs[((c2*NB + b)*LL + ip)*LL + j ] - 1.0f;
  float sjr = zl + zr, sud = zu + zd;
  float hd0 = zv*(RA - 4.0f*RB);
  float hd1 = sjr*RB, hd2 = sud*RB;
  float gd0 = coef[2+c0] + coef[6+c0]*h + beta*hd0;
  float gd1 = coef[2+c1] + coef[6+c1]*h + beta*hd1;
  float gd2 = coef[2+c2] + coef[6+c2]*h + beta*hd2;
  float ca0 = gd0*RA + g*( zv*TAa - 4.0f*zv*TAb );
  float cb0 = gd0*RB + g*( zv*TAb - 4.0f*zv*TBb );
  float cb1 = gd1*RB + g*( sjr*TBb );
  float cb2 = gd2*RB + g*( sud*TBb );
  float contrib = zv*ca0 - 4.0f*zv*cb0 + sjr*cb1 + sud*cb2;

  float vsum = red64(contrib);
  int lane = tid & 63, w = tid >> 6;
  if (lane == 0) part[w] = vsum;
  __syncthreads();
  if (tid == 0) atomicAdd(&ws[640 + b], part[0]+part[1]+part[2]+part[3]);
}

__global__ void k_e(const float* __restrict__ ws, float* __restrict__ out){
  int b = threadIdx.x;
  if (b < 64) {
    out[(size_t)b*4097 + 4096] = ws[640 + b];
  }
}

extern "C" void kernel_launch(void* const* d_in, const int* in_sizes, int n_in,
                              void* d_out, int out_size, void* d_ws, size_t ws_size,
                              hipStream_t stream) {
  const float* xg    = (const float*)d_in[0];
  const int*   signs = (const int*)d_in[1];
  const float* W1    = (const float*)d_in[2];
  const float* b1    = (const float*)d_in[3];
  const float* W2    = (const float*)d_in[4];
  const float* b2    = (const float*)d_in[5];
  const float* W3    = (const float*)d_in[6];
  const float* b3    = (const float*)d_in[7];
  const float* aW1   = (const float*)d_in[8];
  const float* ab1   = (const float*)d_in[9];
  const float* aW2   = (const float*)d_in[10];
  float* ws = (float*)d_ws;
  float* out = (float*)d_out;

  hipMemsetAsync(ws, 0, 704*sizeof(float), stream);  // red + lapl accumulators
  hipLaunchKernelGGL(k_c1, dim3(8192), dim3(256), 0, stream,
                     xg, signs, W1, b1, W2, b2, W3, b3, ws);
  hipLaunchKernelGGL(k_b,  dim3(64),   dim3(64),  0, stream, aW1, ab1, aW2, ws);
  hipLaunchKernelGGL(k_c2, dim3(1024), dim3(256), 0, stream, signs, ws, out);
  hipLaunchKernelGGL(k_e,  dim3(1),    dim3(64),  0, stream, ws, out);
}

// Round 3
// 636.867 us; speedup vs baseline: 1.9209x; 1.9209x over previous
//
#include <hip/hip_runtime.h>
#include <math.h>

typedef unsigned short ushort_t;
typedef unsigned int   u32;
typedef __attribute__((ext_vector_type(8))) short s8v;
typedef __attribute__((ext_vector_type(4))) float f4v;

#define LL 64
#define NB 64
#define NSITE 4096
#define BN 262144
// ws float layout:
//  [0,640)     red[b*10 + {S1,S2,Sd1_c0..3,Sd2_c0..3}]   (atomically accumulated)
//  [640,704)   lapl[b]                                   (atomically accumulated)
//  [704,1344)  coef[b*10 + {alpha,beta,ad_c0..3,bd_c0..3}]
//  [1344, +6*BN) planes: h, RA, RB, TAa, TAb, TBb

__device__ __forceinline__ void gelu3(float u, float &h, float &d, float &e){
  float Phi = 0.5f * (1.0f + erff(u * 0.70710678118654752f));
  float phi = 0.3989422804014327f * __expf(-0.5f * u * u);
  h = u * Phi;
  d = Phi + u * phi;
  e = phi * (2.0f - u * u);
}

__device__ __forceinline__ float redjb16(float v){
  v += __shfl_xor(v, 1);  v += __shfl_xor(v, 2);
  v += __shfl_xor(v, 4);  v += __shfl_xor(v, 8);
  return v;
}
__device__ __forceinline__ float red64(float v){
  v += __shfl_xor(v, 1);  v += __shfl_xor(v, 2);
  v += __shfl_xor(v, 4);  v += __shfl_xor(v, 8);
  v += __shfl_xor(v, 16); v += __shfl_xor(v, 32);
  return v;
}

__device__ __forceinline__ ushort_t bf16rne(float v){
  union { float f; u32 i; } x; x.f = v;
  u32 r = x.i + 0x7FFFu + ((x.i >> 16) & 1u);
  return (ushort_t)(r >> 16);
}
__device__ __forceinline__ float bf2f(ushort_t h){
  union { u32 i; float f; } y; y.i = ((u32)h) << 16; return y.f;
}
// split fp32 -> hi/lo bf16
__device__ __forceinline__ void split2(float v, short &hi, short &lo){
  ushort_t h = bf16rne(v);
  float hf = bf2f(h);
  ushort_t l = bf16rne(v - hf);
  hi = (short)h; lo = (short)l;
}

// ---------------- heavy kernel: one (batch, row, 16-site chunk) ----------------
// grid 16384 = 64 b * 64 i * 4 jchunk ; block 256 (4 waves)
__global__ __launch_bounds__(256, 2) void k_c1(
    const float* __restrict__ xg, const int* __restrict__ signs,
    const float* __restrict__ W1g, const float* __restrict__ b1g,
    const float* __restrict__ W2g, const float* __restrict__ b2g,
    const float* __restrict__ W3g, const float* __restrict__ b3g,
    float* __restrict__ ws)
{
  // A fragments: [kiter(4)][plane(6)][split(2)] blocks of 512 shorts (16 sites x 32 k bf16)
  __shared__ short AF[24576];                 // 48 KB
  __shared__ float waL[128], wbL[128], b1L[128], b2L[128], w3L[128];
  __shared__ float x0L[18], zv0L[18];
  __shared__ float xmL[16], xpL[16], zvmL[16], zvpL[16];
  __shared__ float EP[16][6][4];              // per-site partials per wave

  const int tid  = threadIdx.x;
  const int lane = tid & 63;
  const int w    = tid >> 6;
  const int q    = lane >> 4;
  const int nlo  = lane & 15;

  const int bi = blockIdx.x;
  const int b  = bi >> 8;
  const int rem = bi & 255;
  const int i  = rem >> 2;
  const int jbase = (rem & 3) << 4;
  const int im = (i + 63) & 63, ip = (i + 1) & 63;

  // ---- B fragments: persistent registers, straight from global (L2-resident) ----
  s8v Bh[2][4], Bl[2][4];
  {
    #pragma unroll
    for (int nt = 0; nt < 2; ++nt) {
      int n = w*32 + nt*16 + nlo;
      #pragma unroll
      for (int kt = 0; kt < 4; ++kt) {
        #pragma unroll
        for (int jj = 0; jj < 8; ++jj) {
          int k = kt*32 + q*8 + jj;
          float v = W2g[k*128 + n];
          short hi, lo; split2(v, hi, lo);
          Bh[nt][kt][jj] = hi; Bl[nt][kt][jj] = lo;
        }
      }
    }
  }

  // ---- P0: small staging ----
  if (tid < 128) {
    int k = tid;
    waL[k] = W1g[k] + W1g[256+k] + W1g[384+k];
    wbL[k] = W1g[128+k];
    b1L[k] = b1g[k];
    b2L[k] = b2g[k];
    w3L[k] = W3g[k];
  } else if (tid < 146) {
    int t = tid - 128;
    int jg = (jbase + t - 1) & 63;
    x0L[t] = xg[(size_t)b*NSITE + i*64 + jg];
    int c0 = ((i & 1) << 1) | (jg & 1);
    zv0L[t] = 2.0f * (float)signs[((c0*NB + b)*LL + i)*LL + jg] - 1.0f;
  } else if (tid >= 160 && tid < 176) {
    int t = tid - 160;
    int jg = jbase + t;
    xmL[t] = xg[(size_t)b*NSITE + im*64 + jg];
    int cm = ((im & 1) << 1) | (jg & 1);
    zvmL[t] = 2.0f * (float)signs[((cm*NB + b)*LL + im)*LL + jg] - 1.0f;
  } else if (tid >= 192 && tid < 208) {
    int t = tid - 192;
    int jg = jbase + t;
    xpL[t] = xg[(size_t)b*NSITE + ip*64 + jg];
    int cp = ((ip & 1) << 1) | (jg & 1);
    zvpL[t] = 2.0f * (float)signs[((cp*NB + b)*LL + ip)*LL + jg] - 1.0f;
  }
  __syncthreads();

  // ---- P1: build A fragments (layer-1 gelu + plane scalings + bf16 split) ----
  {
    int s  = tid & 15;
    int ko = tid >> 4;             // k-octet 0..15
    int kt = ko >> 2, kg = ko & 3;
    float p = x0L[1 + s];
    float l = xmL[s] + xpL[s] + x0L[s] + x0L[s + 2] - 4.0f * p;
    int k0 = ko * 8;
    s8v vh[6], vl[6];
    #pragma unroll
    for (int jj = 0; jj < 8; ++jj) {
      float wa = waL[k0 + jj], wb = wbL[k0 + jj];
      float u = p*wa + l*wb + b1L[k0 + jj];
      float h, d, e;
      gelu3(u, h, d, e);
      float pv0 = h;
      float pv1 = d * wa;
      float pv2 = d * wb;
      float pv3 = e * wa * wa;
      float pv4 = e * wa * wb;
      float pv5 = e * wb * wb;
      short hi, lo;
      split2(pv0, hi, lo); vh[0][jj] = hi; vl[0][jj] = lo;
      split2(pv1, hi, lo); vh[1][jj] = hi; vl[1][jj] = lo;
      split2(pv2, hi, lo); vh[2][jj] = hi; vl[2][jj] = lo;
      split2(pv3, hi, lo); vh[3][jj] = hi; vl[3][jj] = lo;
      split2(pv4, hi, lo); vh[4][jj] = hi; vl[4][jj] = lo;
      split2(pv5, hi, lo); vh[5][jj] = hi; vl[5][jj] = lo;
    }
    int eoff = (kg*16 + s) * 8;
    #pragma unroll
    for (int pp = 0; pp < 6; ++pp) {
      *(s8v*)&AF[kt*6144 + pp*1024 + eoff]       = vh[pp];
      *(s8v*)&AF[kt*6144 + pp*1024 + 512 + eoff] = vl[pp];
    }
  }
  __syncthreads();

  // ---- P2: MFMA K-loop (split-bf16: AhBh + AlBh + AhBl) ----
  f4v acc[6][2];
  #pragma unroll
  for (int pp = 0; pp < 6; ++pp)
    #pragma unroll
    for (int nt = 0; nt < 2; ++nt)
      acc[pp][nt] = (f4v){0.f, 0.f, 0.f, 0.f};

  #pragma unroll
  for (int kt = 0; kt < 4; ++kt) {
    #pragma unroll
    for (int pp = 0; pp < 6; ++pp) {
      s8v ah = *(const s8v*)&AF[kt*6144 + pp*1024 + lane*8];
      s8v al = *(const s8v*)&AF[kt*6144 + pp*1024 + 512 + lane*8];
      #pragma unroll
      for (int nt = 0; nt < 2; ++nt) {
        acc[pp][nt] = __builtin_amdgcn_mfma_f32_16x16x32_bf16(ah, Bh[nt][kt], acc[pp][nt], 0, 0, 0);
        acc[pp][nt] = __builtin_amdgcn_mfma_f32_16x16x32_bf16(al, Bh[nt][kt], acc[pp][nt], 0, 0, 0);
        acc[pp][nt] = __builtin_amdgcn_mfma_f32_16x16x32_bf16(ah, Bl[nt][kt], acc[pp][nt], 0, 0, 0);
      }
    }
  }

  // ---- P3: epilogue — layer-2 gelu + j-dots, all in C-layout registers ----
  // C layout: col(n) = lane&15, row(site) = q*4 + r
  {
    float sh[4] = {0,0,0,0}, sA[4] = {0,0,0,0}, sB[4] = {0,0,0,0};
    float sa[4] = {0,0,0,0}, sb[4] = {0,0,0,0}, sc[4] = {0,0,0,0};
    #pragma unroll
    for (int nt = 0; nt < 2; ++nt) {
      int j = w*32 + nt*16 + nlo;
      float b2j = b2L[j], w3j = w3L[j];
      #pragma unroll
      for (int r = 0; r < 4; ++r) {
        float uu = acc[0][nt][r] + b2j;
        float h2, d2, e2;
        gelu3(uu, h2, d2, e2);
        float wd = w3j * d2, we = w3j * e2;
        float A  = acc[1][nt][r], Bv = acc[2][nt][r];
        sh[r] += w3j * h2;
        sA[r] += wd * A;
        sB[r] += wd * Bv;
        sa[r] += we * A * A  + wd * acc[3][nt][r];
        sb[r] += we * A * Bv + wd * acc[4][nt][r];
        sc[r] += we * Bv * Bv + wd * acc[5][nt][r];
      }
    }
    #pragma unroll
    for (int r = 0; r < 4; ++r) {
      sh[r] = redjb16(sh[r]); sA[r] = redjb16(sA[r]); sB[r] = redjb16(sB[r]);
      sa[r] = redjb16(sa[r]); sb[r] = redjb16(sb[r]); sc[r] = redjb16(sc[r]);
    }
    if (nlo == 0) {
      #pragma unroll
      for (int r = 0; r < 4; ++r) {
        int site = q*4 + r;
        EP[site][0][w] = sh[r];
        EP[site][1][w] = sA[r];
        EP[site][2][w] = sB[r];
        EP[site][3][w] = sa[r];
        EP[site][4][w] = sb[r];
        EP[site][5][w] = sc[r];
      }
    }
  }
  __syncthreads();

  // ---- P4: per-site finalize + batch reductions (16 threads) ----
  if (tid < 16) {
    int s = tid;
    float h = 0.f, RA = 0.f, RB = 0.f, TAa = 0.f, TAb = 0.f, TBb = 0.f;
    #pragma unroll
    for (int ww = 0; ww < 4; ++ww) {
      h   += EP[s][0][ww];
      RA  += EP[s][1][ww];
      RB  += EP[s][2][ww];
      TAa += EP[s][3][ww];
      TAb += EP[s][4][ww];
      TBb += EP[s][5][ww];
    }
    h += b3g[0];
    float* P = ws + 1344;
    size_t site = (size_t)b*NSITE + i*64 + jbase + s;
    P[0*BN + site] = h;
    P[1*BN + site] = RA;
    P[2*BN + site] = RB;
    P[3*BN + site] = TAa;
    P[4*BN + site] = TAb;
    P[5*BN + site] = TBb;

    int jg = jbase + s;
    int c0 = ((i & 1) << 1) | (jg & 1);
    float hd[4] = {0.f, 0.f, 0.f, 0.f};
    hd[c0]     = zv0L[1 + s] * (RA - 4.0f*RB);
    hd[c0 ^ 1] = (zv0L[s] + zv0L[s + 2]) * RB;
    hd[c0 ^ 2] = (zvmL[s] + zvpL[s]) * RB;
    float r[10];
    r[0] = h; r[1] = h*h;
    r[2] = hd[0]; r[3] = hd[1]; r[4] = hd[2]; r[5] = hd[3];
    r[6] = h*hd[0]; r[7] = h*hd[1]; r[8] = h*hd[2]; r[9] = h*hd[3];
    #pragma unroll
    for (int n = 0; n < 10; ++n) r[n] = redjb16(r[n]);
    if (s == 0) {
      #pragma unroll
      for (int n = 0; n < 10; ++n) atomicAdd(&ws[b*10 + n], r[n]);
    }
  }
}

// ---------------- tiny per-batch head calculus ----------------
__global__ __launch_bounds__(64, 1) void k_b(
    const float* __restrict__ aW1g, const float* __restrict__ ab1g,
    const float* __restrict__ aW2g, float* __restrict__ ws)
{
  int b = blockIdx.x, k = threadIdx.x;
  const float Nf = 4096.0f, Nm1 = 4095.0f;
  float S1 = ws[b*10+0], S2 = ws[b*10+1];
  float m = S1/Nf, q = S2/Nf;
  float v = (S2 - S1*S1/Nf)/Nm1;
  float w0 = aW1g[k], w1 = aW1g[64+k], w2 = aW1g[128+k];
  float t = m*w0 + v*w1 + q*w2 + ab1g[k];
  float gh, gd, ge;
  gelu3(t, gh, gd, ge);
  float o = aW2g[k];
  float g1o = gd*o, g2o = ge*o;
  float da0 = w0*g1o, da1 = w1*g1o, da2 = w2*g1o;
  float M00 = w0*w0*g2o, M01 = w0*w1*g2o, M02 = w0*w2*g2o;
  float M11 = w1*w1*g2o, M12 = w1*w2*g2o, M22 = w2*w2*g2o;
  da0 = red64(da0); da1 = red64(da1); da2 = red64(da2);
  M00 = red64(M00); M01 = red64(M01); M02 = red64(M02);
  M11 = red64(M11); M12 = red64(M12); M22 = red64(M22);
  if (k == 0) {
    float* coef = ws + 704 + b*10;
    coef[0] = da0/Nf - 2.0f*da1*m/Nm1;                 // alpha
    coef[1] = 2.0f*da1/Nm1 + 2.0f*da2/Nf;              // beta
    #pragma unroll
    for (int c = 0; c < 4; ++c) {
      float s1 = ws[b*10 + 2 + c], s2 = ws[b*10 + 6 + c];
      float md = s1/Nf, qd = 2.0f*s2/Nf;
      float vd = (2.0f*s2 - 2.0f*S1*s1/Nf)/Nm1;
      float dd0 = M00*md + M01*vd + M02*qd;
      float dd1 = M01*md + M11*vd + M12*qd;
      float dd2 = M02*md + M12*vd + M22*qd;
      coef[2+c] = dd0/Nf - 2.0f*(dd1*m + da1*md)/Nm1;  // alpha_dot_c
      coef[6+c] = 2.0f*dd1/Nm1 + 2.0f*dd2/Nf;          // beta_dot_c
    }
  }
}

// ---------------- scalar stencil: grad out + lapl accumulate ----------------
__global__ __launch_bounds__(256, 1) void k_c2(
    const int* __restrict__ signs, float* __restrict__ ws,
    float* __restrict__ out)
{
  __shared__ float part[4];
  int blk = blockIdx.x;
  int b = blk >> 4, rg = blk & 15;
  int tid = threadIdx.x;
  int rl = tid >> 6, j = tid & 63;
  int i = rg*4 + rl;
  const float* coef = ws + 704 + b*10;
  float alpha = coef[0], beta = coef[1];
  const float* P = ws + 1344;
  int base = b*NSITE;
  int im=(i+63)&63, ip=(i+1)&63, jm=(j+63)&63, jp=(j+1)&63;
  int s  = base + i*64 + j;
  int su = base + im*64 + j, sd = base + ip*64 + j;
  int sl = base + i*64 + jm, sr = base + i*64 + jp;
  float h  = P[s], RA = P[BN+s], RB = P[2*BN+s];
  float TAa= P[3*BN+s], TAb = P[4*BN+s], TBb = P[5*BN+s];
  float g  = alpha + beta*h;
  float cb  = g*RB;
  float cbu = (alpha + beta*P[su])*P[2*BN+su];
  float cbd = (alpha + beta*P[sd])*P[2*BN+sd];
  float cbl = (alpha + beta*P[sl])*P[2*BN+sl];
  float cbr = (alpha + beta*P[sr])*P[2*BN+sr];
  float grad = g*RA + (cbu + cbd + cbl + cbr - 4.0f*cb);
  out[(size_t)b*4097 + i*64 + j] = grad;

  int c0 = ((i & 1) << 1) | (j & 1);
  int c1 = c0 ^ 1, c2 = c0 ^ 2;
  float zv = 2.0f*(float)signs[((c0*NB + b)*LL + i )*LL + j ] - 1.0f;
  float zl = 2.0f*(float)signs[((c1*NB + b)*LL + i )*LL + jm] - 1.0f;
  float zr = 2.0f*(float)signs[((c1*NB + b)*LL + i )*LL + jp] - 1.0f;
  float zu = 2.0f*(float)signs[((c2*NB + b)*LL + im)*LL + j ] - 1.0f;
  float zd = 2.0f*(float)signs[((c2*NB + b)*LL + ip)*LL + j ] - 1.0f;
  float sjr = zl + zr, sud = zu + zd;
  float hd0 = zv*(RA - 4.0f*RB);
  float hd1 = sjr*RB, hd2 = sud*RB;
  float gd0 = coef[2+c0] + coef[6+c0]*h + beta*hd0;
  float gd1 = coef[2+c1] + coef[6+c1]*h + beta*hd1;
  float gd2 = coef[2+c2] + coef[6+c2]*h + beta*hd2;
  float ca0 = gd0*RA + g*( zv*TAa - 4.0f*zv*TAb );
  float cb0 = gd0*RB + g*( zv*TAb - 4.0f*zv*TBb );
  float cb1 = gd1*RB + g*( sjr*TBb );
  float cb2 = gd2*RB + g*( sud*TBb );
  float contrib = zv*ca0 - 4.0f*zv*cb0 + sjr*cb1 + sud*cb2;

  float vsum = red64(contrib);
  int lane = tid & 63, w = tid >> 6;
  if (lane == 0) part[w] = vsum;
  __syncthreads();
  if (tid == 0) atomicAdd(&ws[640 + b], part[0]+part[1]+part[2]+part[3]);
}

__global__ void k_e(const float* __restrict__ ws, float* __restrict__ out){
  int b = threadIdx.x;
  if (b < 64) {
    out[(size_t)b*4097 + 4096] = ws[640 + b];
  }
}

extern "C" void kernel_launch(void* const* d_in, const int* in_sizes, int n_in,
                              void* d_out, int out_size, void* d_ws, size_t ws_size,
                              hipStream_t stream) {
  const float* xg    = (const float*)d_in[0];
  const int*   signs = (const int*)d_in[1];
  const float* W1    = (const float*)d_in[2];
  const float* b1    = (const float*)d_in[3];
  const float* W2    = (const float*)d_in[4];
  const float* b2    = (const float*)d_in[5];
  const float* W3    = (const float*)d_in[6];
  const float* b3    = (const float*)d_in[7];
  const float* aW1   = (const float*)d_in[8];
  const float* ab1   = (const float*)d_in[9];
  const float* aW2   = (const float*)d_in[10];
  float* ws = (float*)d_ws;
  float* out = (float*)d_out;

  hipMemsetAsync(ws, 0, 704*sizeof(float), stream);  // red + lapl accumulators
  hipLaunchKernelGGL(k_c1, dim3(16384), dim3(256), 0, stream,
                     xg, signs, W1, b1, W2, b2, W3, b3, ws);
  hipLaunchKernelGGL(k_b,  dim3(64),   dim3(64),  0, stream, aW1, ab1, aW2, ws);
  hipLaunchKernelGGL(k_c2, dim3(1024), dim3(256), 0, stream, signs, ws, out);
  hipLaunchKernelGGL(k_e,  dim3(1),    dim3(64),  0, stream, ws, out);
}

// Round 4
// 531.129 us; speedup vs baseline: 2.3034x; 1.1991x over previous
//
#include <hip/hip_runtime.h>
#include <math.h>

typedef unsigned short ushort_t;
typedef unsigned int   u32;
typedef __attribute__((ext_vector_type(8))) short s8v;
typedef __attribute__((ext_vector_type(4))) float f4v;

#define LL 64
#define NB 64
#define NSITE 4096
#define BN 262144
#define WA_OFF 1408
#define WB_OFF 1536
#define PL_OFF 4096
#define BF_OFF (PL_OFF + 6*BN)   // float index; region holds 2048 s8v hi + 2048 s8v lo
// ws float layout:
//  [0,640)     red[b*10 + {S1,S2,Sd1_c0..3,Sd2_c0..3}]   (atomically accumulated)
//  [640,704)   lapl[b]                                   (atomically accumulated)
//  [1408,1536) wa, [1536,1664) wb                        (k_pre)
//  [4096, +6*BN) planes: h, RA, RB, TAa, TAb, TBb
//  [BF_OFF, +16384) pre-split W2 fragments (bf16 hi then lo)

// fast exact-GELU: value + 1st/2nd derivative. erf via A&S 7.1.26 (|eps|<=1.5e-7),
// single branch, exp shared with the gaussian.
__device__ __forceinline__ void gelu3(float u, float &h, float &d, float &e){
  float E   = __expf(-0.5f * u * u);          // = exp(-z^2), z = u/sqrt(2)
  float phi = 0.3989422804014327f * E;
  float az  = fabsf(u) * 0.70710678118654752f;
  float t   = __builtin_amdgcn_rcpf(1.0f + 0.3275911f * az);
  float p   = t*(0.254829592f + t*(-0.284496736f + t*(1.421413741f + t*(-1.453152027f + t*1.061405429f))));
  float erfabs = 1.0f - p * E;
  float erfv   = __builtin_copysignf(erfabs, u);
  float Phi = 0.5f * (1.0f + erfv);
  h = u * Phi;
  d = Phi + u * phi;
  e = phi * (2.0f - u * u);
}

__device__ __forceinline__ float redjb16(float v){
  v += __shfl_xor(v, 1);  v += __shfl_xor(v, 2);
  v += __shfl_xor(v, 4);  v += __shfl_xor(v, 8);
  return v;
}
__device__ __forceinline__ float red64(float v){
  v += __shfl_xor(v, 1);  v += __shfl_xor(v, 2);
  v += __shfl_xor(v, 4);  v += __shfl_xor(v, 8);
  v += __shfl_xor(v, 16); v += __shfl_xor(v, 32);
  return v;
}

__device__ __forceinline__ ushort_t bf16rne(float v){
  union { float f; u32 i; } x; x.f = v;
  u32 r = x.i + 0x7FFFu + ((x.i >> 16) & 1u);
  return (ushort_t)(r >> 16);
}
__device__ __forceinline__ float bf2f(ushort_t h){
  union { u32 i; float f; } y; y.i = ((u32)h) << 16; return y.f;
}
// precision split (rne hi) — used in one-time prep
__device__ __forceinline__ void split2(float v, short &hi, short &lo){
  ushort_t h = bf16rne(v);
  float hf = bf2f(h);
  ushort_t l = bf16rne(v - hf);
  hi = (short)h; lo = (short)l;
}
// cheap split (trunc hi) — used in the hot loop; residual ~2^-17 rel
__device__ __forceinline__ void split2t(float v, short &hi, short &lo){
  union { float f; u32 i; } x; x.f = v;
  u32 h = x.i >> 16;
  union { u32 i; float f; } y; y.i = h << 16;
  hi = (short)h;
  lo = (short)bf16rne(v - y.f);
}

// ---------------- one-time prep: wa/wb + W2 pre-split in fragment order ----------------
__global__ __launch_bounds__(256, 4) void k_pre(
    const float* __restrict__ W1g, const float* __restrict__ W2g,
    float* __restrict__ ws)
{
  int t = blockIdx.x * 256 + threadIdx.x;     // 0..2047
  if (blockIdx.x == 0 && threadIdx.x < 128) {
    int k = threadIdx.x;
    ws[WA_OFF + k] = W1g[k] + W1g[256+k] + W1g[384+k];
    ws[WB_OFF + k] = W1g[128+k];
  }
  short* BF = (short*)(ws + BF_OFF);
  int w = t >> 9, nt = (t >> 8) & 1, kt = (t >> 6) & 3, lane = t & 63;
  int q = lane >> 4, nlo = lane & 15;
  int n = w*32 + nt*16 + nlo;
  s8v vh, vl;
  #pragma unroll
  for (int jj = 0; jj < 8; ++jj) {
    int k = kt*32 + q*8 + jj;
    short hi, lo; split2(W2g[k*128 + n], hi, lo);
    vh[jj] = hi; vl[jj] = lo;
  }
  *(s8v*)&BF[t*8]         = vh;
  *(s8v*)&BF[16384 + t*8] = vl;
}

// ---------------- heavy kernel: one (batch, row, 16-site chunk) ----------------
// grid 16384 = 64 b * 64 i * 4 jchunk ; block 256 (4 waves); 3 blocks/CU
__global__ __launch_bounds__(256, 3) void k_c1(
    const float* __restrict__ xg, const int* __restrict__ signs,
    const float* __restrict__ b1g, const float* __restrict__ b2g,
    const float* __restrict__ W3g, const float* __restrict__ b3g,
    float* __restrict__ ws)
{
  // A fragments: [kiter(4)][plane(6)][split(2)] blocks of 512 shorts (16 sites x 32 k bf16)
  __shared__ short AF[24576];                 // 48 KB
  __shared__ float b2L[128], w3L[128];
  __shared__ float x0L[18], zv0L[18];
  __shared__ float xmL[16], xpL[16], zvmL[16], zvpL[16];
  __shared__ float EP[16][6][4];

  const int tid  = threadIdx.x;
  const int lane = tid & 63;
  const int w    = tid >> 6;
  const int q    = lane >> 4;
  const int nlo  = lane & 15;

  const int bi = blockIdx.x;
  const int b  = bi >> 8;
  const int rem = bi & 255;
  const int i  = rem >> 2;
  const int jbase = (rem & 3) << 4;
  const int im = (i + 63) & 63, ip = (i + 1) & 63;

  // ---- B fragments: vector loads of pre-split W2 (L1/L2-resident) ----
  s8v Bh[2][4], Bl[2][4];
  {
    const short* BF = (const short*)(ws + BF_OFF);
    #pragma unroll
    for (int nt = 0; nt < 2; ++nt) {
      #pragma unroll
      for (int kt = 0; kt < 4; ++kt) {
        int base = (((w*2 + nt)*4 + kt)*64 + lane) * 8;
        Bh[nt][kt] = *(const s8v*)&BF[base];
        Bl[nt][kt] = *(const s8v*)&BF[16384 + base];
      }
    }
  }

  // ---- P0: small staging ----
  if (tid < 128) {
    b2L[tid] = b2g[tid];
    w3L[tid] = W3g[tid];
  } else if (tid < 146) {
    int t = tid - 128;
    int jg = (jbase + t - 1) & 63;
    x0L[t] = xg[(size_t)b*NSITE + i*64 + jg];
    int c0 = ((i & 1) << 1) | (jg & 1);
    zv0L[t] = 2.0f * (float)signs[((c0*NB + b)*LL + i)*LL + jg] - 1.0f;
  } else if (tid >= 160 && tid < 176) {
    int t = tid - 160;
    int jg = jbase + t;
    xmL[t] = xg[(size_t)b*NSITE + im*64 + jg];
    int cm = ((im & 1) << 1) | (jg & 1);
    zvmL[t] = 2.0f * (float)signs[((cm*NB + b)*LL + im)*LL + jg] - 1.0f;
  } else if (tid >= 192 && tid < 208) {
    int t = tid - 192;
    int jg = jbase + t;
    xpL[t] = xg[(size_t)b*NSITE + ip*64 + jg];
    int cp = ((ip & 1) << 1) | (jg & 1);
    zvpL[t] = 2.0f * (float)signs[((cp*NB + b)*LL + ip)*LL + jg] - 1.0f;
  }
  __syncthreads();

  // ---- P1: build A fragments (layer-1 gelu + plane scalings + bf16 split) ----
  {
    int s  = tid & 15;
    int ko = tid >> 4;             // k-octet 0..15
    int kt = ko >> 2, kg = ko & 3;
    float p = x0L[1 + s];
    float l = xmL[s] + xpL[s] + x0L[s] + x0L[s + 2] - 4.0f * p;
    int k0 = ko * 8;
    float wa8[8], wb8[8], b18[8];
    *(float4*)&wa8[0] = *(const float4*)(ws + WA_OFF + k0);
    *(float4*)&wa8[4] = *(const float4*)(ws + WA_OFF + k0 + 4);
    *(float4*)&wb8[0] = *(const float4*)(ws + WB_OFF + k0);
    *(float4*)&wb8[4] = *(const float4*)(ws + WB_OFF + k0 + 4);
    *(float4*)&b18[0] = *(const float4*)(b1g + k0);
    *(float4*)&b18[4] = *(const float4*)(b1g + k0 + 4);
    s8v vh[6], vl[6];
    #pragma unroll
    for (int jj = 0; jj < 8; ++jj) {
      float wa = wa8[jj], wb = wb8[jj];
      float u = p*wa + l*wb + b18[jj];
      float h, d, e;
      gelu3(u, h, d, e);
      short hi, lo;
      split2t(h,        hi, lo); vh[0][jj] = hi; vl[0][jj] = lo;
      split2t(d*wa,     hi, lo); vh[1][jj] = hi; vl[1][jj] = lo;
      split2t(d*wb,     hi, lo); vh[2][jj] = hi; vl[2][jj] = lo;
      split2t(e*wa*wa,  hi, lo); vh[3][jj] = hi; vl[3][jj] = lo;
      split2t(e*wa*wb,  hi, lo); vh[4][jj] = hi; vl[4][jj] = lo;
      split2t(e*wb*wb,  hi, lo); vh[5][jj] = hi; vl[5][jj] = lo;
    }
    int eoff = (kg*16 + s) * 8;
    #pragma unroll
    for (int pp = 0; pp < 6; ++pp) {
      *(s8v*)&AF[kt*6144 + pp*1024 + eoff]       = vh[pp];
      *(s8v*)&AF[kt*6144 + pp*1024 + 512 + eoff] = vl[pp];
    }
  }
  __syncthreads();

  // ---- P2: MFMA K-loop (split-bf16: AhBh + AlBh + AhBl) ----
  f4v acc[6][2];
  #pragma unroll
  for (int pp = 0; pp < 6; ++pp)
    #pragma unroll
    for (int nt = 0; nt < 2; ++nt)
      acc[pp][nt] = (f4v){0.f, 0.f, 0.f, 0.f};

  #pragma unroll
  for (int kt = 0; kt < 4; ++kt) {
    #pragma unroll
    for (int pp = 0; pp < 6; ++pp) {
      s8v ah = *(const s8v*)&AF[kt*6144 + pp*1024 + lane*8];
      s8v al = *(const s8v*)&AF[kt*6144 + pp*1024 + 512 + lane*8];
      #pragma unroll
      for (int nt = 0; nt < 2; ++nt) {
        acc[pp][nt] = __builtin_amdgcn_mfma_f32_16x16x32_bf16(ah, Bh[nt][kt], acc[pp][nt], 0, 0, 0);
        acc[pp][nt] = __builtin_amdgcn_mfma_f32_16x16x32_bf16(al, Bh[nt][kt], acc[pp][nt], 0, 0, 0);
        acc[pp][nt] = __builtin_amdgcn_mfma_f32_16x16x32_bf16(ah, Bl[nt][kt], acc[pp][nt], 0, 0, 0);
      }
    }
  }

  // ---- P3: epilogue — layer-2 gelu + j-dots, all in C-layout registers ----
  {
    float sh[4] = {0,0,0,0}, sA[4] = {0,0,0,0}, sB[4] = {0,0,0,0};
    float sa[4] = {0,0,0,0}, sb[4] = {0,0,0,0}, sc[4] = {0,0,0,0};
    #pragma unroll
    for (int nt = 0; nt < 2; ++nt) {
      int j = w*32 + nt*16 + nlo;
      float b2j = b2L[j], w3j = w3L[j];
      #pragma unroll
      for (int r = 0; r < 4; ++r) {
        float uu = acc[0][nt][r] + b2j;
        float h2, d2, e2;
        gelu3(uu, h2, d2, e2);
        float wd = w3j * d2, we = w3j * e2;
        float A  = acc[1][nt][r], Bv = acc[2][nt][r];
        sh[r] += w3j * h2;
        sA[r] += wd * A;
        sB[r] += wd * Bv;
        sa[r] += we * A * A  + wd * acc[3][nt][r];
        sb[r] += we * A * Bv + wd * acc[4][nt][r];
        sc[r] += we * Bv * Bv + wd * acc[5][nt][r];
      }
    }
    #pragma unroll
    for (int r = 0; r < 4; ++r) {
      sh[r] = redjb16(sh[r]); sA[r] = redjb16(sA[r]); sB[r] = redjb16(sB[r]);
      sa[r] = redjb16(sa[r]); sb[r] = redjb16(sb[r]); sc[r] = redjb16(sc[r]);
    }
    if (nlo == 0) {
      #pragma unroll
      for (int r = 0; r < 4; ++r) {
        int site = q*4 + r;
        EP[site][0][w] = sh[r];
        EP[site][1][w] = sA[r];
        EP[site][2][w] = sB[r];
        EP[site][3][w] = sa[r];
        EP[site][4][w] = sb[r];
        EP[site][5][w] = sc[r];
      }
    }
  }
  __syncthreads();

  // ---- P4: per-site finalize + batch reductions (16 threads) ----
  if (tid < 16) {
    int s = tid;
    float h = 0.f, RA = 0.f, RB = 0.f, TAa = 0.f, TAb = 0.f, TBb = 0.f;
    #pragma unroll
    for (int ww = 0; ww < 4; ++ww) {
      h   += EP[s][0][ww];
      RA  += EP[s][1][ww];
      RB  += EP[s][2][ww];
      TAa += EP[s][3][ww];
      TAb += EP[s][4][ww];
      TBb += EP[s][5][ww];
    }
    h += b3g[0];
    float* P = ws + PL_OFF;
    size_t site = (size_t)b*NSITE + i*64 + jbase + s;
    P[0*BN + site] = h;
    P[1*BN + site] = RA;
    P[2*BN + site] = RB;
    P[3*BN + site] = TAa;
    P[4*BN + site] = TAb;
    P[5*BN + site] = TBb;

    int jg = jbase + s;
    int c0 = ((i & 1) << 1) | (jg & 1);
    float hd[4] = {0.f, 0.f, 0.f, 0.f};
    hd[c0]     = zv0L[1 + s] * (RA - 4.0f*RB);
    hd[c0 ^ 1] = (zv0L[s] + zv0L[s + 2]) * RB;
    hd[c0 ^ 2] = (zvmL[s] + zvpL[s]) * RB;
    float r[10];
    r[0] = h; r[1] = h*h;
    r[2] = hd[0]; r[3] = hd[1]; r[4] = hd[2]; r[5] = hd[3];
    r[6] = h*hd[0]; r[7] = h*hd[1]; r[8] = h*hd[2]; r[9] = h*hd[3];
    #pragma unroll
    for (int n = 0; n < 10; ++n) r[n] = redjb16(r[n]);
    if (s == 0) {
      #pragma unroll
      for (int n = 0; n < 10; ++n) atomicAdd(&ws[b*10 + n], r[n]);
    }
  }
}

// ---------------- stencil + fused per-batch head calculus ----------------
__global__ __launch_bounds__(256, 1) void k_c2(
    const int* __restrict__ signs,
    const float* __restrict__ aW1g, const float* __restrict__ ab1g,
    const float* __restrict__ aW2g,
    float* __restrict__ ws, float* __restrict__ out)
{
  __shared__ float part[4];
  __shared__ float coefL[10];
  int blk = blockIdx.x;
  int b = blk >> 4, rg = blk & 15;
  int tid = threadIdx.x;

  // head calculus (redundant per block; wave 0 only)
  if (tid < 64) {
    int k = tid;
    const float Nf = 4096.0f, Nm1 = 4095.0f;
    float S1 = ws[b*10+0], S2 = ws[b*10+1];
    float m = S1/Nf, q = S2/Nf;
    float v = (S2 - S1*S1/Nf)/Nm1;
    float w0 = aW1g[k], w1 = aW1g[64+k], w2 = aW1g[128+k];
    float t = m*w0 + v*w1 + q*w2 + ab1g[k];
    float gh, gd, ge;
    gelu3(t, gh, gd, ge);
    float o = aW2g[k];
    float g1o = gd*o, g2o = ge*o;
    float da0 = w0*g1o, da1 = w1*g1o, da2 = w2*g1o;
    float M00 = w0*w0*g2o, M01 = w0*w1*g2o, M02 = w0*w2*g2o;
    float M11 = w1*w1*g2o, M12 = w1*w2*g2o, M22 = w2*w2*g2o;
    da0 = red64(da0); da1 = red64(da1); da2 = red64(da2);
    M00 = red64(M00); M01 = red64(M01); M02 = red64(M02);
    M11 = red64(M11); M12 = red64(M12); M22 = red64(M22);
    if (k == 0) {
      coefL[0] = da0/Nf - 2.0f*da1*m/Nm1;
      coefL[1] = 2.0f*da1/Nm1 + 2.0f*da2/Nf;
      #pragma unroll
      for (int c = 0; c < 4; ++c) {
        float s1 = ws[b*10 + 2 + c], s2 = ws[b*10 + 6 + c];
        float md = s1/Nf, qd = 2.0f*s2/Nf;
        float vd = (2.0f*s2 - 2.0f*S1*s1/Nf)/Nm1;
        float dd0 = M00*md + M01*vd + M02*qd;
        float dd1 = M01*md + M11*vd + M12*qd;
        float dd2 = M02*md + M12*vd + M22*qd;
        coefL[2+c] = dd0/Nf - 2.0f*(dd1*m + da1*md)/Nm1;
        coefL[6+c] = 2.0f*dd1/Nm1 + 2.0f*dd2/Nf;
      }
    }
  }
  __syncthreads();

  int rl = tid >> 6, j = tid & 63;
  int i = rg*4 + rl;
  float alpha = coefL[0], beta = coefL[1];
  const float* P = ws + PL_OFF;
  int base = b*NSITE;
  int im=(i+63)&63, ip=(i+1)&63, jm=(j+63)&63, jp=(j+1)&63;
  int s  = base + i*64 + j;
  int su = base + im*64 + j, sd = base + ip*64 + j;
  int sl = base + i*64 + jm, sr = base + i*64 + jp;
  float h  = P[s], RA = P[BN+s], RB = P[2*BN+s];
  float TAa= P[3*BN+s], TAb = P[4*BN+s], TBb = P[5*BN+s];
  float g  = alpha + beta*h;
  float cb  = g*RB;
  float cbu = (alpha + beta*P[su])*P[2*BN+su];
  float cbd = (alpha + beta*P[sd])*P[2*BN+sd];
  float cbl = (alpha + beta*P[sl])*P[2*BN+sl];
  float cbr = (alpha + beta*P[sr])*P[2*BN+sr];
  float grad = g*RA + (cbu + cbd + cbl + cbr - 4.0f*cb);
  out[(size_t)b*4097 + i*64 + j] = grad;

  int c0 = ((i & 1) << 1) | (j & 1);
  int c1 = c0 ^ 1, c2 = c0 ^ 2;
  float zv = 2.0f*(float)signs[((c0*NB + b)*LL + i )*LL + j ] - 1.0f;
  float zl = 2.0f*(float)signs[((c1*NB + b)*LL + i )*LL + jm] - 1.0f;
  float zr = 2.0f*(float)signs[((c1*NB + b)*LL + i )*LL + jp] - 1.0f;
  float zu = 2.0f*(float)signs[((c2*NB + b)*LL + im)*LL + j ] - 1.0f;
  float zd = 2.0f*(float)signs[((c2*NB + b)*LL + ip)*LL + j ] - 1.0f;
  float sjr = zl + zr, sud = zu + zd;
  float hd0 = zv*(RA - 4.0f*RB);
  float hd1 = sjr*RB, hd2 = sud*RB;
  float gd0 = coefL[2+c0] + coefL[6+c0]*h + beta*hd0;
  float gd1 = coefL[2+c1] + coefL[6+c1]*h + beta*hd1;
  float gd2 = coefL[2+c2] + coefL[6+c2]*h + beta*hd2;
  float ca0 = gd0*RA + g*( zv*TAa - 4.0f*zv*TAb );
  float cb0 = gd0*RB + g*( zv*TAb - 4.0f*zv*TBb );
  float cb1 = gd1*RB + g*( sjr*TBb );
  float cb2 = gd2*RB + g*( sud*TBb );
  float contrib = zv*ca0 - 4.0f*zv*cb0 + sjr*cb1 + sud*cb2;

  float vsum = red64(contrib);
  int lane = tid & 63, wv = tid >> 6;
  if (lane == 0) part[wv] = vsum;
  __syncthreads();
  if (tid == 0) atomicAdd(&ws[640 + b], part[0]+part[1]+part[2]+part[3]);
}

__global__ void k_e(const float* __restrict__ ws, float* __restrict__ out){
  int b = threadIdx.x;
  if (b < 64) {
    out[(size_t)b*4097 + 4096] = ws[640 + b];
  }
}

extern "C" void kernel_launch(void* const* d_in, const int* in_sizes, int n_in,
                              void* d_out, int out_size, void* d_ws, size_t ws_size,
                              hipStream_t stream) {
  const float* xg    = (const float*)d_in[0];
  const int*   signs = (const int*)d_in[1];
  const float* W1    = (const float*)d_in[2];
  const float* b1    = (const float*)d_in[3];
  const float* W2    = (const float*)d_in[4];
  const float* b2    = (const float*)d_in[5];
  const float* W3    = (const float*)d_in[6];
  const float* b3    = (const float*)d_in[7];
  const float* aW1   = (const float*)d_in[8];
  const float* ab1   = (const float*)d_in[9];
  const float* aW2   = (const float*)d_in[10];
  float* ws = (float*)d_ws;
  float* out = (float*)d_out;

  hipMemsetAsync(ws, 0, 704*sizeof(float), stream);  // red + lapl accumulators
  hipLaunchKernelGGL(k_pre, dim3(8),     dim3(256), 0, stream, W1, W2, ws);
  hipLaunchKernelGGL(k_c1,  dim3(16384), dim3(256), 0, stream,
                     xg, signs, b1, b2, W3, b3, ws);
  hipLaunchKernelGGL(k_c2,  dim3(1024),  dim3(256), 0, stream,
                     signs, aW1, ab1, aW2, ws, out);
  hipLaunchKernelGGL(k_e,   dim3(1),     dim3(64),  0, stream, ws, out);
}

// Round 5
// 283.013 us; speedup vs baseline: 4.3227x; 1.8767x over previous
//
#include <hip/hip_runtime.h>
#include <math.h>

typedef unsigned short ushort_t;
typedef unsigned int   u32;
typedef __attribute__((ext_vector_type(8))) short s8v;
typedef __attribute__((ext_vector_type(4))) float f4v;

#define LL 64
#define NB 64
#define NSITE 4096
#define BN 262144
#define WA_OFF 1408
#define WB_OFF 1536
#define PL_OFF 4096
#define BF_OFF (PL_OFF + 6*BN)   // float index; region holds 2048 s8v hi + 2048 s8v lo
// ws float layout:
//  [0,640)     red[b*10 + {S1,S2,Sd1_c0..3,Sd2_c0..3}]   (atomically accumulated)
//  [640,704)   lapl[b]                                   (atomically accumulated)
//  [1408,1536) wa, [1536,1664) wb                        (k_pre)
//  [4096, +6*BN) planes: h, RA, RB, TAa, TAb, TBb
//  [BF_OFF, +16384) pre-split W2 fragments (bf16 hi then lo)

// fast exact-GELU: value + 1st/2nd derivative. erf via A&S 7.1.26 (|eps|<=1.5e-7)
__device__ __forceinline__ void gelu3(float u, float &h, float &d, float &e){
  float E   = __expf(-0.5f * u * u);
  float phi = 0.3989422804014327f * E;
  float az  = fabsf(u) * 0.70710678118654752f;
  float t   = __builtin_amdgcn_rcpf(1.0f + 0.3275911f * az);
  float p   = t*(0.254829592f + t*(-0.284496736f + t*(1.421413741f + t*(-1.453152027f + t*1.061405429f))));
  float erfabs = 1.0f - p * E;
  float erfv   = __builtin_copysignf(erfabs, u);
  float Phi = 0.5f * (1.0f + erfv);
  h = u * Phi;
  d = Phi + u * phi;
  e = phi * (2.0f - u * u);
}

__device__ __forceinline__ float redjb16(float v){
  v += __shfl_xor(v, 1);  v += __shfl_xor(v, 2);
  v += __shfl_xor(v, 4);  v += __shfl_xor(v, 8);
  return v;
}
__device__ __forceinline__ float red64(float v){
  v += __shfl_xor(v, 1);  v += __shfl_xor(v, 2);
  v += __shfl_xor(v, 4);  v += __shfl_xor(v, 8);
  v += __shfl_xor(v, 16); v += __shfl_xor(v, 32);
  return v;
}

__device__ __forceinline__ ushort_t bf16rne(float v){
  union { float f; u32 i; } x; x.f = v;
  u32 r = x.i + 0x7FFFu + ((x.i >> 16) & 1u);
  return (ushort_t)(r >> 16);
}
__device__ __forceinline__ float bf2f(ushort_t h){
  union { u32 i; float f; } y; y.i = ((u32)h) << 16; return y.f;
}
// precision split (rne hi) — one-time prep
__device__ __forceinline__ void split2(float v, short &hi, short &lo){
  ushort_t h = bf16rne(v);
  float hf = bf2f(h);
  ushort_t l = bf16rne(v - hf);
  hi = (short)h; lo = (short)l;
}
// cheap split (trunc hi) — hot loop; residual ~2^-17 rel
__device__ __forceinline__ void split2t(float v, short &hi, short &lo){
  union { float f; u32 i; } x; x.f = v;
  u32 h = x.i >> 16;
  union { u32 i; float f; } y; y.i = h << 16;
  hi = (short)h;
  lo = (short)bf16rne(v - y.f);
}

// ---------------- one-time prep: wa/wb + W2 pre-split in fragment order ----------------
__global__ __launch_bounds__(256, 4) void k_pre(
    const float* __restrict__ W1g, const float* __restrict__ W2g,
    float* __restrict__ ws)
{
  int t = blockIdx.x * 256 + threadIdx.x;     // 0..2047
  if (blockIdx.x == 0 && threadIdx.x < 128) {
    int k = threadIdx.x;
    ws[WA_OFF + k] = W1g[k] + W1g[256+k] + W1g[384+k];
    ws[WB_OFF + k] = W1g[128+k];
  }
  short* BF = (short*)(ws + BF_OFF);
  int w = t >> 9, nt = (t >> 8) & 1, kt = (t >> 6) & 3, lane = t & 63;
  int q = lane >> 4, nlo = lane & 15;
  int n = w*32 + nt*16 + nlo;
  s8v vh, vl;
  #pragma unroll
  for (int jj = 0; jj < 8; ++jj) {
    int k = kt*32 + q*8 + jj;
    short hi, lo; split2(W2g[k*128 + n], hi, lo);
    vh[jj] = hi; vl[jj] = lo;
  }
  *(s8v*)&BF[t*8]         = vh;
  *(s8v*)&BF[16384 + t*8] = vl;
}

// ---------------- heavy kernel: one (batch, row-pair), 8 chunks of 16 sites ----------------
// grid 2048 = 64 b * 32 pairs ; block 256 (4 waves); 3 blocks/CU
__global__ __launch_bounds__(256, 3) void k_c1(
    const float* __restrict__ xg, const int* __restrict__ signs,
    const float* __restrict__ b1g, const float* __restrict__ b2g,
    const float* __restrict__ W3g, const float* __restrict__ b3g,
    float* __restrict__ ws)
{
  // AF: [kt(4)][subplane(9)] x 512 shorts ; subplanes: {0h,0l,1h,1l,2h,2l,3h,4h,5h}
  __shared__ short AF[18432];                 // 36 KB
  __shared__ float xS[4][64], zS[4][64];      // rows i0-1..i0+2
  __shared__ float EP[16][6][4];

  const int tid  = threadIdx.x;
  const int lane = tid & 63;
  const int w    = tid >> 6;
  const int q    = lane >> 4;
  const int nlo  = lane & 15;

  const int blk = blockIdx.x;
  const int b   = blk >> 5;
  const int i0  = (blk & 31) << 1;            // first of two rows

  // ---- per-block register-resident constants ----
  s8v Bh[2][4], Bl[2][4];
  {
    const short* BF = (const short*)(ws + BF_OFF);
    #pragma unroll
    for (int nt = 0; nt < 2; ++nt)
      #pragma unroll
      for (int kt = 0; kt < 4; ++kt) {
        int base = (((w*2 + nt)*4 + kt)*64 + lane) * 8;
        Bh[nt][kt] = *(const s8v*)&BF[base];
        Bl[nt][kt] = *(const s8v*)&BF[16384 + base];
      }
  }
  float wa8[8], wb8[8], b18[8];
  {
    int k0 = (tid >> 4) * 8;
    *(float4*)&wa8[0] = *(const float4*)(ws + WA_OFF + k0);
    *(float4*)&wa8[4] = *(const float4*)(ws + WA_OFF + k0 + 4);
    *(float4*)&wb8[0] = *(const float4*)(ws + WB_OFF + k0);
    *(float4*)&wb8[4] = *(const float4*)(ws + WB_OFF + k0 + 4);
    *(float4*)&b18[0] = *(const float4*)(b1g + k0);
    *(float4*)&b18[4] = *(const float4*)(b1g + k0 + 4);
  }
  float b2j[2], w3j[2];
  #pragma unroll
  for (int nt = 0; nt < 2; ++nt) {
    int j = w*32 + nt*16 + nlo;
    b2j[nt] = b2g[j];
    w3j[nt] = W3g[j];
  }
  float b3v = b3g[0];

  // ---- stage 4 x-rows and 4 z-rows ----
  {
    int r = tid >> 6, j = tid & 63;
    int gr = (i0 - 1 + r) & 63;
    xS[r][j] = xg[(size_t)b*NSITE + gr*64 + j];
    int c = ((gr & 1) << 1) | (j & 1);
    zS[r][j] = 2.0f * (float)signs[((c*NB + b)*LL + gr)*LL + j] - 1.0f;
  }
  __syncthreads();

  float racc[10];
  #pragma unroll
  for (int n = 0; n < 10; ++n) racc[n] = 0.f;

  #pragma unroll 1
  for (int ch = 0; ch < 8; ++ch) {
    const int lr = 1 + (ch >> 2);             // local row 1 or 2
    const int jb = ch & 3;
    const int i  = i0 + (ch >> 2);

    // ---- P1: build A fragments ----
    {
      int s  = tid & 15;
      int ko = tid >> 4;
      int kt = ko >> 2, kg = ko & 3;
      int j = jb*16 + s, jm = (j+63)&63, jp = (j+1)&63;
      float p = xS[lr][j];
      float l = xS[lr-1][j] + xS[lr+1][j] + xS[lr][jm] + xS[lr][jp] - 4.0f*p;
      s8v v0h, v0l, v1h, v1l, v2h, v2l, v3h, v4h, v5h;
      #pragma unroll
      for (int jj = 0; jj < 8; ++jj) {
        float wa = wa8[jj], wb = wb8[jj];
        float u = p*wa + l*wb + b18[jj];
        float h, d, e;
        gelu3(u, h, d, e);
        short hi, lo;
        split2t(h,    hi, lo); v0h[jj] = hi; v0l[jj] = lo;
        split2t(d*wa, hi, lo); v1h[jj] = hi; v1l[jj] = lo;
        split2t(d*wb, hi, lo); v2h[jj] = hi; v2l[jj] = lo;
        v3h[jj] = (short)bf16rne(e*wa*wa);
        v4h[jj] = (short)bf16rne(e*wa*wb);
        v5h[jj] = (short)bf16rne(e*wb*wb);
      }
      short* base = &AF[kt*4608 + (kg*16 + s)*8];
      *(s8v*)&base[0*512] = v0h;  *(s8v*)&base[1*512] = v0l;
      *(s8v*)&base[2*512] = v1h;  *(s8v*)&base[3*512] = v1l;
      *(s8v*)&base[4*512] = v2h;  *(s8v*)&base[5*512] = v2l;
      *(s8v*)&base[6*512] = v3h;  *(s8v*)&base[7*512] = v4h;
      *(s8v*)&base[8*512] = v5h;
    }
    __syncthreads();

    // ---- P2: MFMA ----
    f4v acc[6][2];
    #pragma unroll
    for (int pp = 0; pp < 6; ++pp)
      #pragma unroll
      for (int nt = 0; nt < 2; ++nt)
        acc[pp][nt] = (f4v){0.f, 0.f, 0.f, 0.f};

    #pragma unroll
    for (int kt = 0; kt < 4; ++kt) {
      const short* base = &AF[kt*4608 + lane*8];
      #pragma unroll
      for (int pp = 0; pp < 3; ++pp) {
        s8v ah = *(const s8v*)&base[(2*pp  )*512];
        s8v al = *(const s8v*)&base[(2*pp+1)*512];
        #pragma unroll
        for (int nt = 0; nt < 2; ++nt) {
          acc[pp][nt] = __builtin_amdgcn_mfma_f32_16x16x32_bf16(ah, Bh[nt][kt], acc[pp][nt], 0, 0, 0);
          acc[pp][nt] = __builtin_amdgcn_mfma_f32_16x16x32_bf16(al, Bh[nt][kt], acc[pp][nt], 0, 0, 0);
          acc[pp][nt] = __builtin_amdgcn_mfma_f32_16x16x32_bf16(ah, Bl[nt][kt], acc[pp][nt], 0, 0, 0);
        }
      }
      #pragma unroll
      for (int pp = 3; pp < 6; ++pp) {
        s8v ah = *(const s8v*)&base[(3+pp)*512];
        #pragma unroll
        for (int nt = 0; nt < 2; ++nt)
          acc[pp][nt] = __builtin_amdgcn_mfma_f32_16x16x32_bf16(ah, Bh[nt][kt], acc[pp][nt], 0, 0, 0);
      }
    }

    // ---- P3: epilogue ----
    {
      float sh[4] = {0,0,0,0}, sA[4] = {0,0,0,0}, sB[4] = {0,0,0,0};
      float sa[4] = {0,0,0,0}, sb[4] = {0,0,0,0}, sc[4] = {0,0,0,0};
      #pragma unroll
      for (int nt = 0; nt < 2; ++nt) {
        #pragma unroll
        for (int r = 0; r < 4; ++r) {
          float uu = acc[0][nt][r] + b2j[nt];
          float h2, d2, e2;
          gelu3(uu, h2, d2, e2);
          float wd = w3j[nt] * d2, we = w3j[nt] * e2;
          float A  = acc[1][nt][r], Bv = acc[2][nt][r];
          sh[r] += w3j[nt] * h2;
          sA[r] += wd * A;
          sB[r] += wd * Bv;
          sa[r] += we * A * A   + wd * acc[3][nt][r];
          sb[r] += we * A * Bv  + wd * acc[4][nt][r];
          sc[r] += we * Bv * Bv + wd * acc[5][nt][r];
        }
      }
      #pragma unroll
      for (int r = 0; r < 4; ++r) {
        sh[r] = redjb16(sh[r]); sA[r] = redjb16(sA[r]); sB[r] = redjb16(sB[r]);
        sa[r] = redjb16(sa[r]); sb[r] = redjb16(sb[r]); sc[r] = redjb16(sc[r]);
      }
      if (nlo == 0) {
        #pragma unroll
        for (int r = 0; r < 4; ++r) {
          int site = q*4 + r;
          EP[site][0][w] = sh[r];
          EP[site][1][w] = sA[r];
          EP[site][2][w] = sB[r];
          EP[site][3][w] = sa[r];
          EP[site][4][w] = sb[r];
          EP[site][5][w] = sc[r];
        }
      }
    }
    __syncthreads();

    // ---- P4: per-site finalize + batch accumulation (16 threads) ----
    if (tid < 16) {
      int s = tid;
      float h = 0.f, RA = 0.f, RB = 0.f, TAa = 0.f, TAb = 0.f, TBb = 0.f;
      #pragma unroll
      for (int ww = 0; ww < 4; ++ww) {
        h   += EP[s][0][ww];
        RA  += EP[s][1][ww];
        RB  += EP[s][2][ww];
        TAa += EP[s][3][ww];
        TAb += EP[s][4][ww];
        TBb += EP[s][5][ww];
      }
      h += b3v;
      float* P = ws + PL_OFF;
      int j = jb*16 + s;
      size_t site = (size_t)b*NSITE + i*64 + j;
      P[0*BN + site] = h;
      P[1*BN + site] = RA;
      P[2*BN + site] = RB;
      P[3*BN + site] = TAa;
      P[4*BN + site] = TAb;
      P[5*BN + site] = TBb;

      int jm = (j+63)&63, jp = (j+1)&63;
      int c0 = ((i & 1) << 1) | (j & 1);
      float hd[4] = {0.f, 0.f, 0.f, 0.f};
      hd[c0]     = zS[lr][j] * (RA - 4.0f*RB);
      hd[c0 ^ 1] = (zS[lr][jm] + zS[lr][jp]) * RB;
      hd[c0 ^ 2] = (zS[lr-1][j] + zS[lr+1][j]) * RB;
      racc[0] += h;
      racc[1] += h*h;
      #pragma unroll
      for (int cc = 0; cc < 4; ++cc) {
        racc[2+cc] += hd[cc];
        racc[6+cc] += h*hd[cc];
      }
    }
  }

  // ---- final batch reduction: one atomic set per block ----
  if (tid < 16) {
    #pragma unroll
    for (int n = 0; n < 10; ++n) racc[n] = redjb16(racc[n]);
    if (tid == 0) {
      #pragma unroll
      for (int n = 0; n < 10; ++n) atomicAdd(&ws[b*10 + n], racc[n]);
    }
  }
}

// ---------------- stencil + fused per-batch head calculus ----------------
__global__ __launch_bounds__(256, 1) void k_c2(
    const int* __restrict__ signs,
    const float* __restrict__ aW1g, const float* __restrict__ ab1g,
    const float* __restrict__ aW2g,
    float* __restrict__ ws, float* __restrict__ out)
{
  __shared__ float part[4];
  __shared__ float coefL[10];
  int blk = blockIdx.x;
  int b = blk >> 4, rg = blk & 15;
  int tid = threadIdx.x;

  if (tid < 64) {
    int k = tid;
    const float Nf = 4096.0f, Nm1 = 4095.0f;
    float S1 = ws[b*10+0], S2 = ws[b*10+1];
    float m = S1/Nf, q = S2/Nf;
    float v = (S2 - S1*S1/Nf)/Nm1;
    float w0 = aW1g[k], w1 = aW1g[64+k], w2 = aW1g[128+k];
    float t = m*w0 + v*w1 + q*w2 + ab1g[k];
    float gh, gd, ge;
    gelu3(t, gh, gd, ge);
    float o = aW2g[k];
    float g1o = gd*o, g2o = ge*o;
    float da0 = w0*g1o, da1 = w1*g1o, da2 = w2*g1o;
    float M00 = w0*w0*g2o, M01 = w0*w1*g2o, M02 = w0*w2*g2o;
    float M11 = w1*w1*g2o, M12 = w1*w2*g2o, M22 = w2*w2*g2o;
    da0 = red64(da0); da1 = red64(da1); da2 = red64(da2);
    M00 = red64(M00); M01 = red64(M01); M02 = red64(M02);
    M11 = red64(M11); M12 = red64(M12); M22 = red64(M22);
    if (k == 0) {
      coefL[0] = da0/Nf - 2.0f*da1*m/Nm1;
      coefL[1] = 2.0f*da1/Nm1 + 2.0f*da2/Nf;
      #pragma unroll
      for (int c = 0; c < 4; ++c) {
        float s1 = ws[b*10 + 2 + c], s2 = ws[b*10 + 6 + c];
        float md = s1/Nf, qd = 2.0f*s2/Nf;
        float vd = (2.0f*s2 - 2.0f*S1*s1/Nf)/Nm1;
        float dd0 = M00*md + M01*vd + M02*qd;
        float dd1 = M01*md + M11*vd + M12*qd;
        float dd2 = M02*md + M12*vd + M22*qd;
        coefL[2+c] = dd0/Nf - 2.0f*(dd1*m + da1*md)/Nm1;
        coefL[6+c] = 2.0f*dd1/Nm1 + 2.0f*dd2/Nf;
      }
    }
  }
  __syncthreads();

  int rl = tid >> 6, j = tid & 63;
  int i = rg*4 + rl;
  float alpha = coefL[0], beta = coefL[1];
  const float* P = ws + PL_OFF;
  int base = b*NSITE;
  int im=(i+63)&63, ip=(i+1)&63, jm=(j+63)&63, jp=(j+1)&63;
  int s  = base + i*64 + j;
  int su = base + im*64 + j, sd = base + ip*64 + j;
  int sl = base + i*64 + jm, sr = base + i*64 + jp;
  float h  = P[s], RA = P[BN+s], RB = P[2*BN+s];
  float TAa= P[3*BN+s], TAb = P[4*BN+s], TBb = P[5*BN+s];
  float g  = alpha + beta*h;
  float cb  = g*RB;
  float cbu = (alpha + beta*P[su])*P[2*BN+su];
  float cbd = (alpha + beta*P[sd])*P[2*BN+sd];
  float cbl = (alpha + beta*P[sl])*P[2*BN+sl];
  float cbr = (alpha + beta*P[sr])*P[2*BN+sr];
  float grad = g*RA + (cbu + cbd + cbl + cbr - 4.0f*cb);
  out[(size_t)b*4097 + i*64 + j] = grad;

  int c0 = ((i & 1) << 1) | (j & 1);
  int c1 = c0 ^ 1, c2 = c0 ^ 2;
  float zv = 2.0f*(float)signs[((c0*NB + b)*LL + i )*LL + j ] - 1.0f;
  float zl = 2.0f*(float)signs[((c1*NB + b)*LL + i )*LL + jm] - 1.0f;
  float zr = 2.0f*(float)signs[((c1*NB + b)*LL + i )*LL + jp] - 1.0f;
  float zu = 2.0f*(float)signs[((c2*NB + b)*LL + im)*LL + j ] - 1.0f;
  float zd = 2.0f*(float)signs[((c2*NB + b)*LL + ip)*LL + j ] - 1.0f;
  float sjr = zl + zr, sud = zu + zd;
  float hd0 = zv*(RA - 4.0f*RB);
  float hd1 = sjr*RB, hd2 = sud*RB;
  float gd0 = coefL[2+c0] + coefL[6+c0]*h + beta*hd0;
  float gd1 = coefL[2+c1] + coefL[6+c1]*h + beta*hd1;
  float gd2 = coefL[2+c2] + coefL[6+c2]*h + beta*hd2;
  float ca0 = gd0*RA + g*( zv*TAa - 4.0f*zv*TAb );
  float cb0 = gd0*RB + g*( zv*TAb - 4.0f*zv*TBb );
  float cb1 = gd1*RB + g*( sjr*TBb );
  float cb2 = gd2*RB + g*( sud*TBb );
  float contrib = zv*ca0 - 4.0f*zv*cb0 + sjr*cb1 + sud*cb2;

  float vsum = red64(contrib);
  int lane = tid & 63, wv = tid >> 6;
  if (lane == 0) part[wv] = vsum;
  __syncthreads();
  if (tid == 0) atomicAdd(&ws[640 + b], part[0]+part[1]+part[2]+part[3]);
}

__global__ void k_e(const float* __restrict__ ws, float* __restrict__ out){
  int b = threadIdx.x;
  if (b < 64) {
    out[(size_t)b*4097 + 4096] = ws[640 + b];
  }
}

extern "C" void kernel_launch(void* const* d_in, const int* in_sizes, int n_in,
                              void* d_out, int out_size, void* d_ws, size_t ws_size,
                              hipStream_t stream) {
  const float* xg    = (const float*)d_in[0];
  const int*   signs = (const int*)d_in[1];
  const float* W1    = (const float*)d_in[2];
  const float* b1    = (const float*)d_in[3];
  const float* W2    = (const float*)d_in[4];
  const float* b2    = (const float*)d_in[5];
  const float* W3    = (const float*)d_in[6];
  const float* b3    = (const float*)d_in[7];
  const float* aW1   = (const float*)d_in[8];
  const float* ab1   = (const float*)d_in[9];
  const float* aW2   = (const float*)d_in[10];
  float* ws = (float*)d_ws;
  float* out = (float*)d_out;

  hipMemsetAsync(ws, 0, 704*sizeof(float), stream);  // red + lapl accumulators
  hipLaunchKernelGGL(k_pre, dim3(8),    dim3(256), 0, stream, W1, W2, ws);
  hipLaunchKernelGGL(k_c1,  dim3(2048), dim3(256), 0, stream,
                     xg, signs, b1, b2, W3, b3, ws);
  hipLaunchKernelGGL(k_c2,  dim3(1024), dim3(256), 0, stream,
                     signs, aW1, ab1, aW2, ws, out);
  hipLaunchKernelGGL(k_e,   dim3(1),    dim3(64),  0, stream, ws, out);
}